// Round 1
// baseline (7839.086 us; speedup 1.0000x reference)
//
#include <hip/hip_runtime.h>
#include <math.h>

#define Bsz  8
#define Nseq 1024
#define Cdim 1024
#define Hh   16
#define Dd   64

// ---------------------------------------------------------------------------
// GEMM1: qkv = X(8192x1024) @ Wqkv(1024x3072), epilogue applies RoPE to q,k
// and scatters q,k,v into (B,H,N,D) fp32 buffers.
// 64x64 tile, BK=16, 256 threads, 4x4 per thread. fp32 baseline.
// ---------------------------------------------------------------------------
__global__ __launch_bounds__(256) void gemm_qkv_rope(
    const float* __restrict__ X, const float* __restrict__ W,
    float* __restrict__ qb, float* __restrict__ kbuf, float* __restrict__ vbuf)
{
    const int K = 1024, Nw = 3072;
    __shared__ float As[16][65];   // [k][m]
    __shared__ float Bs[16][65];   // [k][n]
    const int bm  = blockIdx.y * 64;
    const int bn  = blockIdx.x * 64;
    const int tid = threadIdx.x;
    const int ty  = tid >> 4;      // 0..15 (m-group)
    const int tx  = tid & 15;      // 0..15 (n-group)

    float acc[4][4] = {};

    for (int k0 = 0; k0 < K; k0 += 16) {
        for (int i = tid; i < 64 * 16; i += 256) {
            int m = i >> 4, kk = i & 15;
            As[kk][m] = X[(size_t)(bm + m) * K + k0 + kk];
        }
        for (int i = tid; i < 16 * 64; i += 256) {
            int kk = i >> 6, n = i & 63;
            Bs[kk][n] = W[(size_t)(k0 + kk) * Nw + bn + n];
        }
        __syncthreads();
        #pragma unroll
        for (int kk = 0; kk < 16; ++kk) {
            float a[4], b[4];
            #pragma unroll
            for (int i = 0; i < 4; ++i) a[i] = As[kk][ty * 4 + i];
            #pragma unroll
            for (int j = 0; j < 4; ++j) b[j] = Bs[kk][tx * 4 + j];
            #pragma unroll
            for (int i = 0; i < 4; ++i)
                #pragma unroll
                for (int j = 0; j < 4; ++j)
                    acc[i][j] += a[i] * b[j];
        }
        __syncthreads();
    }

    // Epilogue: RoPE (interleaved pairs) on q,k; scatter to (B,H,N,D).
    const int row0 = bm + ty * 4;
    const int col0 = bn + tx * 4;   // even-aligned -> RoPE pairs stay in-thread
    #pragma unroll
    for (int i = 0; i < 4; ++i) {
        int row = row0 + i;
        int b = row >> 10;          // row / 1024
        int n = row & 1023;
        #pragma unroll
        for (int jp = 0; jp < 2; ++jp) {
            int j  = col0 + jp * 2;       // even column of the pair
            float v0 = acc[i][jp * 2];
            float v1 = acc[i][jp * 2 + 1];
            if (j < 2048) {
                int jj = j & 1023;        // position within q- or k-block
                int h = jj >> 6, d = jj & 63;
                int p = d >> 1;
                // omega = 10000^(-p/32) = exp(-p * ln(10000)/32)
                float omega = __expf(-(float)p * 0.2878231366242557f);
                float fr = (float)n * omega;
                float sv, cv;
                sincosf(fr, &sv, &cv);
                float o0 = v0 * cv - v1 * sv;
                float o1 = v1 * cv + v0 * sv;
                float* dst = (j < 1024) ? qb : kbuf;
                size_t idx = (((size_t)b * Hh + h) * Nseq + n) * Dd + d;
                dst[idx]     = o0;
                dst[idx + 1] = o1;
            } else {
                int jj = j - 2048;
                int h = jj >> 6, d = jj & 63;
                size_t idx = (((size_t)b * Hh + h) * Nseq + n) * Dd + d;
                vbuf[idx]     = v0;
                vbuf[idx + 1] = v1;
            }
        }
    }
}

// ---------------------------------------------------------------------------
// Attention: one block per (query row n, head bh). 256 threads.
// scores -> softmax -> P@V, all fp32, scores staged in LDS.
// ---------------------------------------------------------------------------
__global__ __launch_bounds__(256) void attn_kernel(
    const float* __restrict__ qb, const float* __restrict__ kbuf,
    const float* __restrict__ vbuf, float* __restrict__ ao)
{
    const int n   = blockIdx.x;   // query position
    const int bh  = blockIdx.y;   // b*H + h
    const int tid = threadIdx.x;

    __shared__ float qs[64];
    __shared__ float s[Nseq];
    __shared__ float red[256];

    const size_t base = (size_t)bh * Nseq * Dd;

    if (tid < 64) qs[tid] = qb[base + (size_t)n * Dd + tid] * 0.125f; // 1/sqrt(64)
    __syncthreads();

    // scores s[k] = (q/8) . k_row
    for (int k = tid; k < Nseq; k += 256) {
        const float* kr = kbuf + base + (size_t)k * Dd;
        float dot = 0.f;
        #pragma unroll
        for (int d = 0; d < 64; ++d) dot += qs[d] * kr[d];
        s[k] = dot;
    }
    __syncthreads();

    // block max
    float lm = -1e30f;
    for (int k = tid; k < Nseq; k += 256) lm = fmaxf(lm, s[k]);
    red[tid] = lm;
    __syncthreads();
    for (int off = 128; off > 0; off >>= 1) {
        if (tid < off) red[tid] = fmaxf(red[tid], red[tid + off]);
        __syncthreads();
    }
    float m = red[0];
    __syncthreads();

    // exp + block sum
    float ls = 0.f;
    for (int k = tid; k < Nseq; k += 256) {
        float e = __expf(s[k] - m);
        s[k] = e;
        ls += e;
    }
    red[tid] = ls;
    __syncthreads();
    for (int off = 128; off > 0; off >>= 1) {
        if (tid < off) red[tid] += red[tid + off];
        __syncthreads();
    }
    float inv = 1.f / red[0];
    __syncthreads();

    // O = P @ V : thread handles (d = tid&63) over a 256-key chunk
    const int d = tid & 63, chunk = tid >> 6;
    float accv = 0.f;
    const float* vr = vbuf + base + (size_t)chunk * 256 * Dd;
    for (int k = 0; k < 256; ++k)
        accv += s[chunk * 256 + k] * vr[(size_t)k * Dd + d];
    red[tid] = accv;
    __syncthreads();
    if (tid < 64) {
        float o = (red[tid] + red[tid + 64] + red[tid + 128] + red[tid + 192]) * inv;
        int b = bh >> 4, h = bh & 15;
        ao[((size_t)(b * Nseq + n)) * Cdim + h * Dd + d] = o;  // merged heads (B,N,C)
    }
}

// ---------------------------------------------------------------------------
// GEMM2: out = AO(8192x1024) @ Wproj(1024x1024) + bias
// ---------------------------------------------------------------------------
__global__ __launch_bounds__(256) void gemm_proj(
    const float* __restrict__ A, const float* __restrict__ W,
    const float* __restrict__ bias, float* __restrict__ out)
{
    const int K = 1024, Nw = 1024;
    __shared__ float As[16][65];
    __shared__ float Bs[16][65];
    const int bm  = blockIdx.y * 64;
    const int bn  = blockIdx.x * 64;
    const int tid = threadIdx.x;
    const int ty  = tid >> 4;
    const int tx  = tid & 15;

    float acc[4][4] = {};

    for (int k0 = 0; k0 < K; k0 += 16) {
        for (int i = tid; i < 64 * 16; i += 256) {
            int m = i >> 4, kk = i & 15;
            As[kk][m] = A[(size_t)(bm + m) * K + k0 + kk];
        }
        for (int i = tid; i < 16 * 64; i += 256) {
            int kk = i >> 6, n = i & 63;
            Bs[kk][n] = W[(size_t)(k0 + kk) * Nw + bn + n];
        }
        __syncthreads();
        #pragma unroll
        for (int kk = 0; kk < 16; ++kk) {
            float a[4], b[4];
            #pragma unroll
            for (int i = 0; i < 4; ++i) a[i] = As[kk][ty * 4 + i];
            #pragma unroll
            for (int j = 0; j < 4; ++j) b[j] = Bs[kk][tx * 4 + j];
            #pragma unroll
            for (int i = 0; i < 4; ++i)
                #pragma unroll
                for (int j = 0; j < 4; ++j)
                    acc[i][j] += a[i] * b[j];
        }
        __syncthreads();
    }

    const int row0 = bm + ty * 4;
    const int col0 = bn + tx * 4;
    #pragma unroll
    for (int i = 0; i < 4; ++i) {
        #pragma unroll
        for (int j = 0; j < 4; ++j) {
            int row = row0 + i, col = col0 + j;
            out[(size_t)row * Nw + col] = acc[i][j] + bias[col];
        }
    }
}

extern "C" void kernel_launch(void* const* d_in, const int* in_sizes, int n_in,
                              void* d_out, int out_size, void* d_ws, size_t ws_size,
                              hipStream_t stream) {
    const float* x      = (const float*)d_in[0];
    const float* w_qkv  = (const float*)d_in[1];
    const float* w_proj = (const float*)d_in[2];
    const float* b_proj = (const float*)d_in[3];
    float* out = (float*)d_out;

    // workspace layout: q | k | v | attn_out, each B*H*N*D fp32 = 32 MiB
    size_t seg = (size_t)Bsz * Hh * Nseq * Dd;
    float* qb   = (float*)d_ws;
    float* kbuf = qb + seg;
    float* vbuf = kbuf + seg;
    float* ao   = vbuf + seg;

    dim3 g1(3072 / 64, 8192 / 64);
    gemm_qkv_rope<<<g1, dim3(256), 0, stream>>>(x, w_qkv, qb, kbuf, vbuf);

    dim3 ga(Nseq, Bsz * Hh);
    attn_kernel<<<ga, dim3(256), 0, stream>>>(qb, kbuf, vbuf, ao);

    dim3 g2(1024 / 64, 8192 / 64);
    gemm_proj<<<g2, dim3(256), 0, stream>>>(ao, w_proj, b_proj, out);
}

// Round 2
// 2054.194 us; speedup vs baseline: 3.8161x; 3.8161x over previous
//
#include <hip/hip_runtime.h>
#include <math.h>

#define Bsz  8
#define Nseq 1024
#define Cdim 1024
#define Hh   16
#define Dd   64

// ---------------------------------------------------------------------------
// GEMM1: qkv = X(8192x1024) @ Wqkv(1024x3072), epilogue applies RoPE to q,k
// and scatters q,k,v into (B,H,N,D) fp32 buffers.
// ---------------------------------------------------------------------------
__global__ __launch_bounds__(256) void gemm_qkv_rope(
    const float* __restrict__ X, const float* __restrict__ W,
    float* __restrict__ qb, float* __restrict__ kbuf, float* __restrict__ vbuf)
{
    const int K = 1024, Nw = 3072;
    __shared__ float As[16][65];   // [k][m]
    __shared__ float Bs[16][65];   // [k][n]
    const int bm  = blockIdx.y * 64;
    const int bn  = blockIdx.x * 64;
    const int tid = threadIdx.x;
    const int ty  = tid >> 4;
    const int tx  = tid & 15;

    float acc[4][4] = {};

    for (int k0 = 0; k0 < K; k0 += 16) {
        for (int i = tid; i < 64 * 16; i += 256) {
            int m = i >> 4, kk = i & 15;
            As[kk][m] = X[(size_t)(bm + m) * K + k0 + kk];
        }
        for (int i = tid; i < 16 * 64; i += 256) {
            int kk = i >> 6, n = i & 63;
            Bs[kk][n] = W[(size_t)(k0 + kk) * Nw + bn + n];
        }
        __syncthreads();
        #pragma unroll
        for (int kk = 0; kk < 16; ++kk) {
            float a[4], b[4];
            #pragma unroll
            for (int i = 0; i < 4; ++i) a[i] = As[kk][ty * 4 + i];
            #pragma unroll
            for (int j = 0; j < 4; ++j) b[j] = Bs[kk][tx * 4 + j];
            #pragma unroll
            for (int i = 0; i < 4; ++i)
                #pragma unroll
                for (int j = 0; j < 4; ++j)
                    acc[i][j] += a[i] * b[j];
        }
        __syncthreads();
    }

    const int row0 = bm + ty * 4;
    const int col0 = bn + tx * 4;
    #pragma unroll
    for (int i = 0; i < 4; ++i) {
        int row = row0 + i;
        int b = row >> 10;
        int n = row & 1023;
        #pragma unroll
        for (int jp = 0; jp < 2; ++jp) {
            int j  = col0 + jp * 2;
            float v0 = acc[i][jp * 2];
            float v1 = acc[i][jp * 2 + 1];
            if (j < 2048) {
                int jj = j & 1023;
                int h = jj >> 6, d = jj & 63;
                int p = d >> 1;
                float omega = __expf(-(float)p * 0.2878231366242557f);
                float fr = (float)n * omega;
                float sv, cv;
                sincosf(fr, &sv, &cv);
                float o0 = v0 * cv - v1 * sv;
                float o1 = v1 * cv + v0 * sv;
                float* dst = (j < 1024) ? qb : kbuf;
                size_t idx = (((size_t)b * Hh + h) * Nseq + n) * Dd + d;
                dst[idx]     = o0;
                dst[idx + 1] = o1;
            } else {
                int jj = j - 2048;
                int h = jj >> 6, d = jj & 63;
                size_t idx = (((size_t)b * Hh + h) * Nseq + n) * Dd + d;
                vbuf[idx]     = v0;
                vbuf[idx + 1] = v1;
            }
        }
    }
}

// ---------------------------------------------------------------------------
// Flash-style attention. Block = (q-tile of 64 rows, one bh head).
// 256 threads, 4x4 register tile per thread for both 64x64x64 GEMMs.
// Online softmax across 16 k-tiles. K/V share one LDS buffer.
// LDS: 3 x 64x68 fp32 = 51 KB -> 3 blocks/CU.
// ---------------------------------------------------------------------------
__global__ __launch_bounds__(256) void attn_flash(
    const float* __restrict__ qb, const float* __restrict__ kbuf,
    const float* __restrict__ vbuf, float* __restrict__ ao)
{
    const int qt  = blockIdx.x;   // 0..15
    const int bh  = blockIdx.y;   // 0..127
    const int tid = threadIdx.x;
    const int ty  = tid >> 4;     // 0..15
    const int tx  = tid & 15;     // 0..15

    __shared__ float Qs[64][68];   // [d][q]   (transposed, scaled)
    __shared__ float KVs[64][68];  // K phase: [d][k] ; V phase: [k][d]
    __shared__ float Ps[64][68];   // [k][q]   (transposed P)

    const size_t base = (size_t)bh * (Nseq * Dd);
    const int q0 = qt * 64;

    // load Q tile transposed, pre-scaled by 1/sqrt(D)=0.125
    for (int i = tid; i < 1024; i += 256) {
        int r  = i >> 4;      // q row in tile
        int c4 = i & 15;      // float4 group along d
        float4 v = ((const float4*)(qb + base + (size_t)(q0 + r) * Dd))[c4];
        Qs[c4 * 4 + 0][r] = v.x * 0.125f;
        Qs[c4 * 4 + 1][r] = v.y * 0.125f;
        Qs[c4 * 4 + 2][r] = v.z * 0.125f;
        Qs[c4 * 4 + 3][r] = v.w * 0.125f;
    }

    float m_i[4], l_i[4];
    float o[4][4] = {};
    #pragma unroll
    for (int i = 0; i < 4; ++i) { m_i[i] = -1e30f; l_i[i] = 0.f; }

    for (int kt = 0; kt < 16; ++kt) {
        __syncthreads();   // prev iteration done with KVs (V) and Ps
        // load K tile transposed: KVs[d][k]
        for (int i = tid; i < 1024; i += 256) {
            int r  = i >> 4;     // key row
            int c4 = i & 15;
            float4 v = ((const float4*)(kbuf + base + (size_t)(kt * 64 + r) * Dd))[c4];
            KVs[c4 * 4 + 0][r] = v.x;
            KVs[c4 * 4 + 1][r] = v.y;
            KVs[c4 * 4 + 2][r] = v.z;
            KVs[c4 * 4 + 3][r] = v.w;
        }
        __syncthreads();   // K ready (also covers Qs on kt==0)

        // S = (Q/8) K^T  : 64x64x64
        float s[4][4] = {};
        #pragma unroll
        for (int d = 0; d < 64; ++d) {
            float a[4], b[4];
            #pragma unroll
            for (int i = 0; i < 4; ++i) a[i] = Qs[d][ty * 4 + i];
            #pragma unroll
            for (int j = 0; j < 4; ++j) b[j] = KVs[d][tx * 4 + j];
            #pragma unroll
            for (int i = 0; i < 4; ++i)
                #pragma unroll
                for (int j = 0; j < 4; ++j)
                    s[i][j] += a[i] * b[j];
        }

        // online softmax per q-row (row = ty*4+i, 16 tx lanes share a row)
        #pragma unroll
        for (int i = 0; i < 4; ++i) {
            float lm = fmaxf(fmaxf(s[i][0], s[i][1]), fmaxf(s[i][2], s[i][3]));
            #pragma unroll
            for (int off = 1; off < 16; off <<= 1)
                lm = fmaxf(lm, __shfl_xor(lm, off));
            float m_new = fmaxf(m_i[i], lm);
            float alpha = __expf(m_i[i] - m_new);
            float lsum = 0.f;
            #pragma unroll
            for (int j = 0; j < 4; ++j) {
                s[i][j] = __expf(s[i][j] - m_new);
                lsum += s[i][j];
            }
            #pragma unroll
            for (int off = 1; off < 16; off <<= 1)
                lsum += __shfl_xor(lsum, off);
            l_i[i] = l_i[i] * alpha + lsum;
            m_i[i] = m_new;
            #pragma unroll
            for (int j = 0; j < 4; ++j) o[i][j] *= alpha;
            // store P transposed: Ps[k][q]
            #pragma unroll
            for (int j = 0; j < 4; ++j)
                Ps[tx * 4 + j][ty * 4 + i] = s[i][j];
        }
        __syncthreads();   // everyone done reading KVs(K); Ps half-written ok

        // load V tile row-major: KVs[k][d]
        for (int i = tid; i < 1024; i += 256) {
            int r  = i >> 4;
            int c4 = i & 15;
            float4 v = ((const float4*)(vbuf + base + (size_t)(kt * 64 + r) * Dd))[c4];
            ((float4*)&KVs[r][0])[c4] = v;
        }
        __syncthreads();   // V + Ps ready

        // O += P @ V : 64x64x64
        #pragma unroll
        for (int kk = 0; kk < 64; ++kk) {
            float a[4], b[4];
            #pragma unroll
            for (int i = 0; i < 4; ++i) a[i] = Ps[kk][ty * 4 + i];
            #pragma unroll
            for (int j = 0; j < 4; ++j) b[j] = KVs[kk][tx * 4 + j];
            #pragma unroll
            for (int i = 0; i < 4; ++i)
                #pragma unroll
                for (int j = 0; j < 4; ++j)
                    o[i][j] += a[i] * b[j];
        }
    }

    // epilogue: normalize and write merged-head layout (B,N,C)
    const int b = bh >> 4, h = bh & 15;
    #pragma unroll
    for (int i = 0; i < 4; ++i) {
        float inv = 1.f / l_i[i];
        int q = q0 + ty * 4 + i;
        #pragma unroll
        for (int j = 0; j < 4; ++j) {
            int d = tx * 4 + j;
            ao[((size_t)(b * Nseq + q)) * Cdim + h * Dd + d] = o[i][j] * inv;
        }
    }
}

// ---------------------------------------------------------------------------
// GEMM2: out = AO(8192x1024) @ Wproj(1024x1024) + bias
// ---------------------------------------------------------------------------
__global__ __launch_bounds__(256) void gemm_proj(
    const float* __restrict__ A, const float* __restrict__ W,
    const float* __restrict__ bias, float* __restrict__ out)
{
    const int K = 1024, Nw = 1024;
    __shared__ float As[16][65];
    __shared__ float Bs[16][65];
    const int bm  = blockIdx.y * 64;
    const int bn  = blockIdx.x * 64;
    const int tid = threadIdx.x;
    const int ty  = tid >> 4;
    const int tx  = tid & 15;

    float acc[4][4] = {};

    for (int k0 = 0; k0 < K; k0 += 16) {
        for (int i = tid; i < 64 * 16; i += 256) {
            int m = i >> 4, kk = i & 15;
            As[kk][m] = A[(size_t)(bm + m) * K + k0 + kk];
        }
        for (int i = tid; i < 16 * 64; i += 256) {
            int kk = i >> 6, n = i & 63;
            Bs[kk][n] = W[(size_t)(k0 + kk) * Nw + bn + n];
        }
        __syncthreads();
        #pragma unroll
        for (int kk = 0; kk < 16; ++kk) {
            float a[4], b[4];
            #pragma unroll
            for (int i = 0; i < 4; ++i) a[i] = As[kk][ty * 4 + i];
            #pragma unroll
            for (int j = 0; j < 4; ++j) b[j] = Bs[kk][tx * 4 + j];
            #pragma unroll
            for (int i = 0; i < 4; ++i)
                #pragma unroll
                for (int j = 0; j < 4; ++j)
                    acc[i][j] += a[i] * b[j];
        }
        __syncthreads();
    }

    const int row0 = bm + ty * 4;
    const int col0 = bn + tx * 4;
    #pragma unroll
    for (int i = 0; i < 4; ++i) {
        #pragma unroll
        for (int j = 0; j < 4; ++j) {
            int row = row0 + i, col = col0 + j;
            out[(size_t)row * Nw + col] = acc[i][j] + bias[col];
        }
    }
}

extern "C" void kernel_launch(void* const* d_in, const int* in_sizes, int n_in,
                              void* d_out, int out_size, void* d_ws, size_t ws_size,
                              hipStream_t stream) {
    const float* x      = (const float*)d_in[0];
    const float* w_qkv  = (const float*)d_in[1];
    const float* w_proj = (const float*)d_in[2];
    const float* b_proj = (const float*)d_in[3];
    float* out = (float*)d_out;

    size_t seg = (size_t)Bsz * Hh * Nseq * Dd;
    float* qb   = (float*)d_ws;
    float* kbuf = qb + seg;
    float* vbuf = kbuf + seg;
    float* ao   = vbuf + seg;

    dim3 g1(3072 / 64, 8192 / 64);
    gemm_qkv_rope<<<g1, dim3(256), 0, stream>>>(x, w_qkv, qb, kbuf, vbuf);

    dim3 ga(16, Bsz * Hh);
    attn_flash<<<ga, dim3(256), 0, stream>>>(qb, kbuf, vbuf, ao);

    dim3 g2(1024 / 64, 8192 / 64);
    gemm_proj<<<g2, dim3(256), 0, stream>>>(ao, w_proj, b_proj, out);
}

// Round 3
// 767.407 us; speedup vs baseline: 10.2150x; 2.6768x over previous
//
#include <hip/hip_runtime.h>
#include <hip/hip_bf16.h>
#include <math.h>

#define Bsz  8
#define Nseq 1024
#define Cdim 1024
#define Hh   16
#define Dd   64

typedef short short8 __attribute__((ext_vector_type(8)));
typedef float floatx4 __attribute__((ext_vector_type(4)));

__device__ __forceinline__ unsigned short f2bf(float f) {
    __hip_bfloat16 h = __float2bfloat16(f);
    return __builtin_bit_cast(unsigned short, h);
}
__device__ __forceinline__ float b2f(unsigned short u) {
    return __uint_as_float(((unsigned)u) << 16);
}

// async 16B global -> LDS. LDS dest is wave-uniform base + lane*16 (HW rule).
__device__ __forceinline__ void async16(const void* g, void* l) {
    __builtin_amdgcn_global_load_lds(
        (const __attribute__((address_space(1))) unsigned int*)g,
        (__attribute__((address_space(3))) unsigned int*)l, 16, 0, 0);
}

// ---------------------------------------------------------------------------
// fp32 -> bf16 elementwise (X)
// ---------------------------------------------------------------------------
__global__ __launch_bounds__(256) void convert_bf16(
    const float* __restrict__ in, unsigned short* __restrict__ out)
{
    int i = blockIdx.x * 256 + threadIdx.x;
    float4 v = ((const float4*)in)[i];
    ushort4 u;
    u.x = f2bf(v.x); u.y = f2bf(v.y); u.z = f2bf(v.z); u.w = f2bf(v.w);
    ((ushort4*)out)[i] = u;
}

// ---------------------------------------------------------------------------
// W (R x Ccols) fp32 -> Wt (Ccols x R) bf16
// ---------------------------------------------------------------------------
__global__ __launch_bounds__(256) void transpose_bf16(
    const float* __restrict__ in, unsigned short* __restrict__ out, int R, int Ccols)
{
    __shared__ float T[64][65];
    int c0 = blockIdx.x * 64, r0 = blockIdx.y * 64;
    for (int i = threadIdx.x; i < 4096; i += 256) {
        int r = i >> 6, c = i & 63;
        T[r][c] = in[(size_t)(r0 + r) * Ccols + c0 + c];
    }
    __syncthreads();
    for (int i = threadIdx.x; i < 4096; i += 256) {
        int rr = i >> 6, cc = i & 63;
        out[(size_t)(c0 + rr) * R + r0 + cc] = f2bf(T[cc][rr]);
    }
}

// ---------------------------------------------------------------------------
// bf16 MFMA GEMM (m97 structure): C(Mx?) = A(Mx1024) @ Bt(Nx1024)^T
// 128x128 tile, BK=32, 4 waves, 16x16x32 MFMA, 4x4 frags per wave.
// MODE 0: N=3072, epilogue RoPE + scatter q/k/v (bf16, B,H,N,D layout)
// MODE 1: N=1024, epilogue + bias -> fp32 out
// ---------------------------------------------------------------------------
template <int MODE>
__global__ __launch_bounds__(256) void gemm_bf16(
    const unsigned short* __restrict__ A, const unsigned short* __restrict__ Bt,
    const float* __restrict__ bias,
    unsigned short* __restrict__ qb, unsigned short* __restrict__ kb,
    unsigned short* __restrict__ vb, float* __restrict__ out)
{
    const int K = 1024;
    __shared__ short As[128][32];   // [m][k], contiguous k (no padding: DMA rule)
    __shared__ short Bs[128][32];   // [n][k]
    const int tid  = threadIdx.x;
    const int wave = tid >> 6, lane = tid & 63;
    const int ml = lane & 15, quad = lane >> 4;
    const int wm = wave >> 1, wn = wave & 1;
    const int bm = blockIdx.y * 128, bn = blockIdx.x * 128;

    floatx4 acc[4][4] = {};

    for (int k0 = 0; k0 < K; k0 += 32) {
        #pragma unroll
        for (int t = 0; t < 2; ++t) {
            int r0  = wave * 16 + t * 64;
            int row = r0 + (lane >> 2);
            int kp  = k0 + (lane & 3) * 8;
            async16(A  + (size_t)(bm + row) * K + kp, &As[r0][0]);
            async16(Bt + (size_t)(bn + row) * K + kp, &Bs[r0][0]);
        }
        __syncthreads();

        short8 araw[4], braw[4];
        #pragma unroll
        for (int mi = 0; mi < 4; ++mi)
            araw[mi] = *(const short8*)&As[wm * 64 + mi * 16 + ml][quad * 8];
        #pragma unroll
        for (int ni = 0; ni < 4; ++ni)
            braw[ni] = *(const short8*)&Bs[wn * 64 + ni * 16 + ml][quad * 8];
        #pragma unroll
        for (int mi = 0; mi < 4; ++mi)
            #pragma unroll
            for (int ni = 0; ni < 4; ++ni)
                acc[mi][ni] = __builtin_amdgcn_mfma_f32_16x16x32_bf16(
                    araw[mi], braw[ni], acc[mi][ni], 0, 0, 0);
        __syncthreads();
    }

    if (MODE == 0) {
        // RoPE + scatter. Block's 128 cols lie in exactly one of q/k/v.
        const int region = bn >> 10;                 // 0=q, 1=k, 2=v
        unsigned short* dst = (region == 0) ? qb : ((region == 1) ? kb : vb);
        #pragma unroll
        for (int ni = 0; ni < 4; ++ni) {
            int col = bn + wn * 64 + ni * 16 + ml;
            int jj  = col & 1023;
            int h = jj >> 6, d = jj & 63;
            float omega = 0.f, sgn = 0.f;
            if (region < 2) {
                omega = __expf(-(float)(d >> 1) * 0.2878231366242557f);
                sgn   = (col & 1) ? 1.f : -1.f;      // even: o=v*c-p*s, odd: o=v*c+p*s
            }
            #pragma unroll
            for (int mi = 0; mi < 4; ++mi) {
                #pragma unroll
                for (int r = 0; r < 4; ++r) {
                    int row = bm + wm * 64 + mi * 16 + quad * 4 + r;
                    int b = row >> 10, n = row & 1023;
                    float val = acc[mi][ni][r];
                    size_t idx = (((size_t)b * Hh + h) * Nseq + n) * Dd + d;
                    if (region == 2) {
                        dst[idx] = f2bf(val);
                    } else {
                        float partner = __shfl_xor(val, 1);
                        float sv, cv;
                        sincosf((float)n * omega, &sv, &cv);
                        dst[idx] = f2bf(val * cv + sgn * partner * sv);
                    }
                }
            }
        }
    } else {
        #pragma unroll
        for (int ni = 0; ni < 4; ++ni) {
            int col = bn + wn * 64 + ni * 16 + ml;
            float bv = bias[col];
            #pragma unroll
            for (int mi = 0; mi < 4; ++mi)
                #pragma unroll
                for (int r = 0; r < 4; ++r) {
                    int row = bm + wm * 64 + mi * 16 + quad * 4 + r;
                    out[(size_t)row * 1024 + col] = acc[mi][ni][r] + bv;
                }
        }
    }
}

// ---------------------------------------------------------------------------
// Flash attention, fp32 compute, bf16 q/k/v in, bf16 out.
// ---------------------------------------------------------------------------
__global__ __launch_bounds__(256) void attn_flash(
    const unsigned short* __restrict__ qb, const unsigned short* __restrict__ kb,
    const unsigned short* __restrict__ vb, unsigned short* __restrict__ ao)
{
    const int qt  = blockIdx.x;   // 0..15
    const int bh  = blockIdx.y;   // 0..127
    const int tid = threadIdx.x;
    const int ty  = tid >> 4;
    const int tx  = tid & 15;

    __shared__ float Qs[64][68];   // [d][q] transposed, scaled
    __shared__ float KVs[64][68];  // K phase: [d][k]; V phase: [k][d]
    __shared__ float Ps[64][68];   // [k][q]

    const size_t base = (size_t)bh * (Nseq * Dd);
    const int q0 = qt * 64;

    for (int i = tid; i < 1024; i += 256) {
        int r = i >> 4, c4 = i & 15;
        ushort4 u = ((const ushort4*)(qb + base + (size_t)(q0 + r) * Dd))[c4];
        Qs[c4 * 4 + 0][r] = b2f(u.x) * 0.125f;
        Qs[c4 * 4 + 1][r] = b2f(u.y) * 0.125f;
        Qs[c4 * 4 + 2][r] = b2f(u.z) * 0.125f;
        Qs[c4 * 4 + 3][r] = b2f(u.w) * 0.125f;
    }

    float m_i[4], l_i[4];
    float o[4][4] = {};
    #pragma unroll
    for (int i = 0; i < 4; ++i) { m_i[i] = -1e30f; l_i[i] = 0.f; }

    for (int kt = 0; kt < 16; ++kt) {
        __syncthreads();
        for (int i = tid; i < 1024; i += 256) {
            int r = i >> 4, c4 = i & 15;
            ushort4 u = ((const ushort4*)(kb + base + (size_t)(kt * 64 + r) * Dd))[c4];
            KVs[c4 * 4 + 0][r] = b2f(u.x);
            KVs[c4 * 4 + 1][r] = b2f(u.y);
            KVs[c4 * 4 + 2][r] = b2f(u.z);
            KVs[c4 * 4 + 3][r] = b2f(u.w);
        }
        __syncthreads();

        float s[4][4] = {};
        #pragma unroll
        for (int d = 0; d < 64; ++d) {
            float a[4], b[4];
            #pragma unroll
            for (int i = 0; i < 4; ++i) a[i] = Qs[d][ty * 4 + i];
            #pragma unroll
            for (int j = 0; j < 4; ++j) b[j] = KVs[d][tx * 4 + j];
            #pragma unroll
            for (int i = 0; i < 4; ++i)
                #pragma unroll
                for (int j = 0; j < 4; ++j)
                    s[i][j] += a[i] * b[j];
        }

        #pragma unroll
        for (int i = 0; i < 4; ++i) {
            float lm = fmaxf(fmaxf(s[i][0], s[i][1]), fmaxf(s[i][2], s[i][3]));
            #pragma unroll
            for (int off = 1; off < 16; off <<= 1)
                lm = fmaxf(lm, __shfl_xor(lm, off));
            float m_new = fmaxf(m_i[i], lm);
            float alpha = __expf(m_i[i] - m_new);
            float lsum = 0.f;
            #pragma unroll
            for (int j = 0; j < 4; ++j) {
                s[i][j] = __expf(s[i][j] - m_new);
                lsum += s[i][j];
            }
            #pragma unroll
            for (int off = 1; off < 16; off <<= 1)
                lsum += __shfl_xor(lsum, off);
            l_i[i] = l_i[i] * alpha + lsum;
            m_i[i] = m_new;
            #pragma unroll
            for (int j = 0; j < 4; ++j) o[i][j] *= alpha;
            #pragma unroll
            for (int j = 0; j < 4; ++j)
                Ps[tx * 4 + j][ty * 4 + i] = s[i][j];
        }
        __syncthreads();

        for (int i = tid; i < 1024; i += 256) {
            int r = i >> 4, c4 = i & 15;
            ushort4 u = ((const ushort4*)(vb + base + (size_t)(kt * 64 + r) * Dd))[c4];
            ((float4*)&KVs[r][0])[c4] = make_float4(b2f(u.x), b2f(u.y), b2f(u.z), b2f(u.w));
        }
        __syncthreads();

        #pragma unroll
        for (int kk = 0; kk < 64; ++kk) {
            float a[4], b[4];
            #pragma unroll
            for (int i = 0; i < 4; ++i) a[i] = Ps[kk][ty * 4 + i];
            #pragma unroll
            for (int j = 0; j < 4; ++j) b[j] = KVs[kk][tx * 4 + j];
            #pragma unroll
            for (int i = 0; i < 4; ++i)
                #pragma unroll
                for (int j = 0; j < 4; ++j)
                    o[i][j] += a[i] * b[j];
        }
    }

    const int b = bh >> 4, h = bh & 15;
    #pragma unroll
    for (int i = 0; i < 4; ++i) {
        float inv = 1.f / l_i[i];
        int q = q0 + ty * 4 + i;
        #pragma unroll
        for (int j = 0; j < 4; ++j) {
            int d = tx * 4 + j;
            ao[((size_t)(b * Nseq + q)) * Cdim + h * Dd + d] = f2bf(o[i][j] * inv);
        }
    }
}

extern "C" void kernel_launch(void* const* d_in, const int* in_sizes, int n_in,
                              void* d_out, int out_size, void* d_ws, size_t ws_size,
                              hipStream_t stream) {
    const float* x      = (const float*)d_in[0];
    const float* w_qkv  = (const float*)d_in[1];
    const float* w_proj = (const float*)d_in[2];
    const float* b_proj = (const float*)d_in[3];
    float* out = (float*)d_out;

    const size_t M8 = (size_t)8 * 1024 * 1024;
    unsigned short* qb     = (unsigned short*)d_ws;
    unsigned short* kb     = qb + M8;
    unsigned short* vb     = kb + M8;
    unsigned short* xb     = vb + M8;
    unsigned short* wqkvt  = xb + M8;            // 3072 x 1024
    unsigned short* wprojt = wqkvt + 3 * 1024 * 1024;  // 1024 x 1024
    unsigned short* aob    = wprojt + 1024 * 1024;     // 8192 x 1024

    convert_bf16<<<8192, 256, 0, stream>>>(x, xb);
    transpose_bf16<<<dim3(48, 16), 256, 0, stream>>>(w_qkv, wqkvt, 1024, 3072);
    transpose_bf16<<<dim3(16, 16), 256, 0, stream>>>(w_proj, wprojt, 1024, 1024);

    gemm_bf16<0><<<dim3(24, 64), 256, 0, stream>>>(xb, wqkvt, nullptr, qb, kb, vb, nullptr);

    attn_flash<<<dim3(16, 128), 256, 0, stream>>>(qb, kb, vb, aob);

    gemm_bf16<1><<<dim3(8, 64), 256, 0, stream>>>(aob, wprojt, b_proj,
                                                  nullptr, nullptr, nullptr, out);
}